// Round 2
// baseline (46.848 us; speedup 1.0000x reference)
//
#include <hip/hip_runtime.h>
#include <stdint.h>

#define BB   32
#define HH   64
#define WW   2048
#define HOUT 128   // 2*(HH-1)+2

__device__ __forceinline__ unsigned int flip_f(float f) {
    unsigned int u = __float_as_uint(f);
    return (u & 0x80000000u) ? ~u : (u | 0x80000000u);
}
__device__ __forceinline__ float unflip_f(unsigned int u) {
    return (u & 0x80000000u) ? __uint_as_float(u ^ 0x80000000u)
                             : __uint_as_float(~u);
}

__global__ void k_init_min(unsigned int* ws) {
    if (threadIdx.x == 0 && blockIdx.x == 0) ws[0] = 0xFFFFFFFFu; // flip(+inf)
}

__global__ void k_min_reduce(const float4* __restrict__ x4, int n4,
                             unsigned int* __restrict__ ws) {
    float m = 3.4e38f;
    for (int i = blockIdx.x * blockDim.x + threadIdx.x; i < n4;
         i += gridDim.x * blockDim.x) {
        float4 v = x4[i];
        m = fminf(m, fminf(fminf(v.x, v.y), fminf(v.z, v.w)));
    }
    // wave-64 shuffle reduce
    #pragma unroll
    for (int off = 32; off > 0; off >>= 1)
        m = fminf(m, __shfl_down(m, off, 64));
    __shared__ float smem[4];
    int lane = threadIdx.x & 63, wid = threadIdx.x >> 6;
    if (lane == 0) smem[wid] = m;
    __syncthreads();
    if (threadIdx.x == 0) {
        float bm = fminf(fminf(smem[0], smem[1]), fminf(smem[2], smem[3]));
        atomicMin(ws, flip_f(bm));
    }
}

__global__ void __launch_bounds__(256)
k_upsample(const float* __restrict__ x, float* __restrict__ out,
           const unsigned int* __restrict__ ws) {
    // padding contributes zeros to the window tensor -> gmin = min(min(x), 0)
    const float gmin = fminf(unflip_f(ws[0]), 0.0f);

    int idx = blockIdx.x * blockDim.x + threadIdx.x;   // 2,097,152 total
    int b   = idx >> 16;          // HOUT*WW/4 = 65536 float4 per batch
    int rem = idx & 65535;
    int ho  = rem >> 9;           // WW/4 = 512 float4 per row
    int wq  = rem & 511;
    int w0  = wq << 2;

    float4* o4 = (float4*)(out + ((size_t)b * HOUT + ho) * WW + w0);

    if ((ho & 1) == 0 || ho == 127) {
        // copy row: even rows -> x[ho/2]; rows 126,127 -> x[63] (126>>1==63, 127>>1==63)
        int h = ho >> 1;
        const float4* src = (const float4*)(x + ((size_t)b * HH + h) * WW + w0);
        *o4 = *src;
        return;
    }

    // odd row 1..125: pixels row h = (ho-1)/2, from x rows h and h+1
    int h = ho >> 1;
    const float* rA = x + ((size_t)b * HH + h) * WW + w0;
    const float* rB = rA + WW;

    float4 a = *(const float4*)rA;
    float4 c4 = *(const float4*)rB;
    float aL = (w0 > 0)       ? rA[-1] : 0.0f;
    float bL = (w0 > 0)       ? rB[-1] : 0.0f;
    float aR = (w0 + 4 < WW)  ? rA[4]  : 0.0f;
    float bR = (w0 + 4 < WW)  ? rB[4]  : 0.0f;

    float av[6] = {aL, a.x, a.y, a.z, a.w, aR};
    float bv[6] = {bL, c4.x, c4.y, c4.z, c4.w, bR};

    const float BASE_D = 0.49306869139523979f;  // exp(-sqrt(2)/2)
    const float BASE_C = 0.60653065971263342f;  // exp(-0.5)

    float4 res;
    float* rp = &res.x;
    #pragma unroll
    for (int c = 0; c < 4; ++c) {
        float num = 0.0f, den = 0.0f;
        float vs[6]   = {av[c], av[c + 1], av[c + 2],
                         bv[c], bv[c + 1], bv[c + 2]};
        const float bs[6] = {BASE_D, BASE_C, BASE_D, BASE_D, BASE_C, BASE_D};
        #pragma unroll
        for (int k = 0; k < 6; ++k) {
            float wv = vs[k];
            float wi = bs[k] * (2.0f / (1.0f + __expf(wv - gmin)));
            wi = (wv != 0.0f) ? wi : 0.0f;
            num += wv * wi;
            den += wi;
        }
        den = (den == 0.0f) ? 1.0f : den;
        rp[c] = num / den;
    }
    *o4 = res;
}

extern "C" void kernel_launch(void* const* d_in, const int* in_sizes, int n_in,
                              void* d_out, int out_size, void* d_ws, size_t ws_size,
                              hipStream_t stream) {
    const float* x = (const float*)d_in[0];
    float* out = (float*)d_out;
    unsigned int* ws = (unsigned int*)d_ws;

    hipLaunchKernelGGL(k_init_min, dim3(1), dim3(1), 0, stream, ws);

    int n4 = BB * HH * WW / 4;  // 1,048,576
    hipLaunchKernelGGL(k_min_reduce, dim3(1024), dim3(256), 0, stream,
                       (const float4*)x, n4, ws);

    int total4 = BB * HOUT * WW / 4;  // 2,097,152
    hipLaunchKernelGGL(k_upsample, dim3(total4 / 256), dim3(256), 0, stream,
                       x, out, ws);
}